// Round 2
// baseline (73.259 us; speedup 1.0000x reference)
//
#include <hip/hip_runtime.h>

// Problem constants: B=4, C=128, H=64, W=64, L=16, K=64, CD=8. C == L*CD.
#define Bn   4
#define Cn   128
#define HWn  4096
#define Ln   16
#define Kn   64
#define CDn  8
#define QUANT_ELEMS (Bn * Cn * HWn)   // 2,097,152
#define PIX_PER_THREAD 4              // consecutive pixels -> float4 I/O

typedef float v4 __attribute__((ext_vector_type(4)));

// Straight-through forward == hard_symbols: skip softmax/soft path entirely.
// argmin over sqrt(d2) == argmin over d2 (sqrt monotone) -> skip sqrt.
// Each thread: 4 consecutive pixels of one (b,l). Per-element math is the
// identical sub -> fma chain (d ascending) + k-ascending strict-< argmin as
// the verified R1 kernel, so argmin/tie behavior is bit-identical.
__global__ __launch_bounds__(256)
void soft_to_hard_encoder_kernel(const float* __restrict__ z,
                                 const float* __restrict__ codes,
                                 float* __restrict__ out) {
    __shared__ __align__(16) float sc[Kn * CDn];  // codes[l] : 64 x 8 (2 KB)

    const int t        = threadIdx.x;
    const int pixblock = blockIdx.x & 3;          // 4 blocks of 1024 pix
    const int bl       = blockIdx.x >> 2;
    const int l        = bl & (Ln - 1);
    const int b        = bl >> 4;
    const int pix0     = pixblock * 1024 + t * 4; // 4 consecutive pixels

    // Stage codes[l] into LDS.
    for (int i = t; i < Kn * CDn; i += 256)
        sc[i] = codes[l * Kn * CDn + i];
    __syncthreads();

    // Load 8 channels x 4 pixels as float4 (lane-dense 1 KiB/wave per d).
    const int cbase = b * Cn + l * CDn;
    v4 hz[CDn];
    const v4* z4 = (const v4*)z;
    #pragma unroll
    for (int d = 0; d < CDn; ++d)
        hz[d] = z4[(size_t)(cbase + d) * (HWn / 4) + (pix0 >> 2)];

    // Argmin over 64 codes, 4 pixels at once (vector lanes = pixels).
    v4 best = {3.402823466e+38f, 3.402823466e+38f, 3.402823466e+38f, 3.402823466e+38f};
    int bi0 = 0, bi1 = 0, bi2 = 0, bi3 = 0;
    #pragma unroll 4
    for (int k = 0; k < Kn; ++k) {
        float c[CDn];
        #pragma unroll
        for (int d = 0; d < CDn; ++d) c[d] = sc[k * CDn + d];
        v4 s = {0.f, 0.f, 0.f, 0.f};
        #pragma unroll
        for (int d = 0; d < CDn; ++d) {
            v4 df = hz[d] - c[d];
            s = __builtin_elementwise_fma(df, df, s);
        }
        if (s.x < best.x) { best.x = s.x; bi0 = k; }
        if (s.y < best.y) { best.y = s.y; bi1 = k; }
        if (s.z < best.z) { best.z = s.z; bi2 = k; }
        if (s.w < best.w) { best.w = s.w; bi3 = k; }
    }

    // Gather the 4 winning code rows, transpose to per-d float4, store dense.
    float cp[PIX_PER_THREAD][CDn];
    const int bis[PIX_PER_THREAD] = {bi0, bi1, bi2, bi3};
    #pragma unroll
    for (int p = 0; p < PIX_PER_THREAD; ++p) {
        v4 ca = *(const v4*)&sc[bis[p] * CDn];
        v4 cb = *(const v4*)&sc[bis[p] * CDn + 4];
        cp[p][0] = ca.x; cp[p][1] = ca.y; cp[p][2] = ca.z; cp[p][3] = ca.w;
        cp[p][4] = cb.x; cp[p][5] = cb.y; cp[p][6] = cb.z; cp[p][7] = cb.w;
    }
    v4* out4 = (v4*)out;
    #pragma unroll
    for (int d = 0; d < CDn; ++d) {
        v4 o = {cp[0][d], cp[1][d], cp[2][d], cp[3][d]};
        out4[(size_t)(cbase + d) * (HWn / 4) + (pix0 >> 2)] = o;
    }

    // idxes (b,h,w,l) as float, after the quantized block (stride-16 scatter;
    // only 1 MB total, L2 merges partial lines).
    #pragma unroll
    for (int p = 0; p < PIX_PER_THREAD; ++p)
        out[QUANT_ELEMS + (size_t)(b * HWn + pix0 + p) * Ln + l] = (float)bis[p];
}

extern "C" void kernel_launch(void* const* d_in, const int* in_sizes, int n_in,
                              void* d_out, int out_size, void* d_ws, size_t ws_size,
                              hipStream_t stream) {
    const float* z     = (const float*)d_in[0];  // (4,128,64,64) fp32
    const float* codes = (const float*)d_in[1];  // (16,64,8) fp32
    float* out         = (float*)d_out;

    const int blocks = Bn * Ln * (HWn / (256 * PIX_PER_THREAD));  // 256
    soft_to_hard_encoder_kernel<<<blocks, 256, 0, stream>>>(z, codes, out);
}